// Round 10
// baseline (431.905 us; speedup 1.0000x reference)
//
#include <hip/hip_runtime.h>
#include <hip/hip_fp16.h>

#define FIN 6
#define HC 64
#define LAYERS 3
#define CAP 48       // bucket slots per node; Poisson(12) tail @48 ~ 8e-16
#define ECHUNK 2048  // edges per scatter block

typedef _Float16 f16x8 __attribute__((ext_vector_type(8)));
typedef float f32x4 __attribute__((ext_vector_type(4)));
typedef unsigned int u32x2 __attribute__((ext_vector_type(2)));

__global__ void PathfindingGNN_17274358464713_kernel() {}

// ---- fused: partitioned edge scatter (8 node-range passes, XCD-local L2 slices)
//      + encoder (h16, 4ch/thread) ---- [round-7 proven]
__global__ __launch_bounds__(256) void k_enc_scatter(const float* __restrict__ x,
                                                     const float* __restrict__ Wenc,
                                                     const float* __restrict__ benc,
                                                     __half* __restrict__ h16,
                                                     int Nn,
                                                     const int* __restrict__ src,
                                                     const int* __restrict__ dst,
                                                     const float* __restrict__ ea,
                                                     int* __restrict__ counts,
                                                     unsigned int* __restrict__ bucket,
                                                     int E, int edgeB8) {
  if ((int)blockIdx.x < edgeB8) {
    const int part = blockIdx.x & 7;
    const int chunk = blockIdx.x >> 3;
    const int e0 = chunk * ECHUNK;
    const int e1 = min(e0 + ECHUNK, E);
    int dv[8], sv[8];
    float eav[8];
#pragma unroll
    for (int j = 0; j < 8; ++j) {
      int e = e0 + (int)threadIdx.x + j * 256;
      if (e < e1) {
        dv[j] = __builtin_nontemporal_load(&dst[e]);
        sv[j] = __builtin_nontemporal_load(&src[e]);
        eav[j] = __builtin_nontemporal_load(&ea[e]);
      } else {
        dv[j] = -1;
      }
    }
#pragma unroll
    for (int j = 0; j < 8; ++j) {
      int d = dv[j];
      if (d < 0) continue;
      int p8 = (int)(((unsigned int)d * 41u) >> 19);
      if (p8 != part) continue;
      int p = atomicAdd(&counts[d], 1);
      if (p < CAP) {
        unsigned int q = (unsigned int)(eav[j] * 32767.0f + 0.5f);  // ea in [0,1)
        bucket[d * CAP + p] = (unsigned int)sv[j] | (q << 17);
      }
    }
    return;
  }
  int idx = (blockIdx.x - edgeB8) * 256 + threadIdx.x;
  if (idx >= Nn * (HC / 4)) return;
  int n = idx >> 4, cp = (idx & 15) * 4;
  float4 bv = *(const float4*)&benc[cp];
  float s0 = bv.x, s1 = bv.y, s2 = bv.z, s3 = bv.w;
#pragma unroll
  for (int f = 0; f < FIN; ++f) {
    float xv = x[n * FIN + f];
    float4 wv = *(const float4*)&Wenc[f * HC + cp];
    s0 = fmaf(xv, wv.x, s0);
    s1 = fmaf(xv, wv.y, s1);
    s2 = fmaf(xv, wv.z, s2);
    s3 = fmaf(xv, wv.w, s3);
  }
  __half2 h01 = __floats2half2_rn(s0, s1);
  __half2 h23 = __floats2half2_rn(s2, s3);
  u32x2 u;
  u.x = *(unsigned int*)&h01;
  u.y = *(unsigned int*)&h23;
  *(u32x2*)&h16[n * HC + cp] = u;  // cached: k_layer re-reads h16 ~12x
}

// ---------------- fused layer: BARRIER-FREE wave pipeline ----
// 64 nodes/block, 256 threads (4 waves). Structure: stage Wt -> ONE barrier ->
// each wave runs gather -> GEMM -> epilogue -> store fully independently.
// Legal because GEMM of wave w reads only Asm rows 16w..16w+15, written only by
// wave w's own quarters (intra-wave LDS ordering via lgkmcnt). Removes the
// post-gather block barrier that made every wave wait on the block's slowest
// quarter (r9: grid = 6.1 blocks/CU = single residency round, straggler-bound,
// Occupancy 30%). Gather: quarter-wave (16 lanes, 4ch/lane) owns 4 nodes;
// 16 uncond. bucket uint4 prefetches + up to 64 guarded h-row loads, one window.
__global__ __launch_bounds__(256, 6) void k_layer(const __half* __restrict__ h16,
                                                  const int* __restrict__ counts,
                                                  const unsigned int* __restrict__ bucket,
                                                  const float* __restrict__ We, const float* __restrict__ be,
                                                  const float* __restrict__ W, const float* __restrict__ b,
                                                  const float* __restrict__ gam, const float* __restrict__ bet,
                                                  const float* __restrict__ mean, const float* __restrict__ var,
                                                  __half* __restrict__ out16, int Nn,
                                                  int last, const float* __restrict__ Wp1,
                                                  const float* __restrict__ bp1, const float* __restrict__ Wp2,
                                                  const float* __restrict__ bp2, float* __restrict__ pred) {
  __shared__ alignas(16) __half Wt[64][136];  // Wt[col][k] = W[k][col], k<128
  __shared__ alignas(16) __half Asm[64][72];  // agg fp16 (wave-private row bands)

  const int tid = threadIdx.x;
  const int nb = blockIdx.x * 64;
  const int w = tid >> 6;
  const int lr = tid & 15;
  const int lg = (tid >> 4) & 3;
  const float inv15 = 1.0f / 32767.0f;

  // issue gather-critical + GEMM-self loads FIRST (in flight across Wt staging)
  int ldn = min(nb + w * 16 + lr, Nn - 1);
  int ldc = min(counts[ldn], CAP);
  const int arow = ldn;
  f16x8 aself0 = *(const f16x8*)&h16[arow * HC + lg * 8];
  f16x8 aself1 = *(const f16x8*)&h16[arow * HC + 32 + lg * 8];

  // stage Wt, then the ONLY pre-GEMM barrier
  for (int i = tid; i < 128 * 64; i += 256) {
    int k = i >> 6, col = i & 63;
    Wt[col][k] = __float2half(W[i]);
  }
  __syncthreads();

  // ---- gather (wave-independent from here) ----
  {
    const int q = (tid >> 4) & 3;
    const int ch0 = (tid & 15) * 4;
    const float4 wev = *(const float4*)&We[ch0];
    const float4 bev = *(const float4*)&be[ch0];

#define PROC(vv, mm) {                                                      \
    unsigned int v_ = (vv);                                                 \
    u32x2 hu = *(const u32x2*)&h16[(v_ & 0x1FFFFu) * HC + ch0];             \
    unsigned int hx_ = hu.x, hy_ = hu.y;                                    \
    float qf = (float)(v_ >> 17) * inv15;                                   \
    float2 f01 = __half22float2(*(const __half2*)&hx_);                     \
    float2 f23 = __half22float2(*(const __half2*)&hy_);                     \
    mm[0] = fmaxf(mm[0], f01.x * fmaf(qf, wev.x, bev.x));                   \
    mm[1] = fmaxf(mm[1], f01.y * fmaf(qf, wev.y, bev.y));                   \
    mm[2] = fmaxf(mm[2], f23.x * fmaf(qf, wev.z, bev.z));                   \
    mm[3] = fmaxf(mm[3], f23.y * fmaf(qf, wev.w, bev.w)); }

    int cn0 = __shfl(ldc, q * 4 + 0, 64);
    int cn1 = __shfl(ldc, q * 4 + 1, 64);
    int cn2 = __shfl(ldc, q * 4 + 2, 64);
    int cn3 = __shfl(ldc, q * 4 + 3, 64);
    const int r00 = min(nb + w * 16 + q * 4 + 0, Nn - 1) * CAP;
    const int r01 = min(nb + w * 16 + q * 4 + 1, Nn - 1) * CAP;
    const int r02 = min(nb + w * 16 + q * 4 + 2, Nn - 1) * CAP;
    const int r03 = min(nb + w * 16 + q * 4 + 3, Nn - 1) * CAP;
    uint4 p0[4], p1[4], p2[4], p3[4];
#pragma unroll
    for (int j = 0; j < 4; ++j) p0[j] = *(const uint4*)&bucket[r00 + 4 * j];
#pragma unroll
    for (int j = 0; j < 4; ++j) p1[j] = *(const uint4*)&bucket[r01 + 4 * j];
#pragma unroll
    for (int j = 0; j < 4; ++j) p2[j] = *(const uint4*)&bucket[r02 + 4 * j];
#pragma unroll
    for (int j = 0; j < 4; ++j) p3[j] = *(const uint4*)&bucket[r03 + 4 * j];
    float m0[4], m1[4], m2[4], m3[4];
#pragma unroll
    for (int i = 0; i < 4; ++i) { m0[i] = -INFINITY; m1[i] = -INFINITY; m2[i] = -INFINITY; m3[i] = -INFINITY; }
#pragma unroll
    for (int j = 0; j < 4; ++j) {
      const int base = 4 * j;
      if (cn0 > base)     PROC(p0[j].x, m0)
      if (cn1 > base)     PROC(p1[j].x, m1)
      if (cn2 > base)     PROC(p2[j].x, m2)
      if (cn3 > base)     PROC(p3[j].x, m3)
      if (cn0 > base + 1) PROC(p0[j].y, m0)
      if (cn1 > base + 1) PROC(p1[j].y, m1)
      if (cn2 > base + 1) PROC(p2[j].y, m2)
      if (cn3 > base + 1) PROC(p3[j].y, m3)
      if (cn0 > base + 2) PROC(p0[j].z, m0)
      if (cn1 > base + 2) PROC(p1[j].z, m1)
      if (cn2 > base + 2) PROC(p2[j].z, m2)
      if (cn3 > base + 2) PROC(p3[j].z, m3)
      if (cn0 > base + 3) PROC(p0[j].w, m0)
      if (cn1 > base + 3) PROC(p1[j].w, m1)
      if (cn2 > base + 3) PROC(p2[j].w, m2)
      if (cn3 > base + 3) PROC(p3[j].w, m3)
    }
    // tails (cnt > 16, rare)
    for (int r = r00 + 16, r1 = r00 + cn0; r < r1; ++r) PROC(bucket[r], m0)
    for (int r = r01 + 16, r1 = r01 + cn1; r < r1; ++r) PROC(bucket[r], m1)
    for (int r = r02 + 16, r1 = r02 + cn2; r < r1; ++r) PROC(bucket[r], m2)
    for (int r = r03 + 16, r1 = r03 + cn3; r < r1; ++r) PROC(bucket[r], m3)
#undef PROC
#define STORE(mm, i) {                                                      \
    __half2 h01 = __floats2half2_rn((mm[0] == -INFINITY) ? 0.f : mm[0],     \
                                    (mm[1] == -INFINITY) ? 0.f : mm[1]);    \
    __half2 h23 = __floats2half2_rn((mm[2] == -INFINITY) ? 0.f : mm[2],     \
                                    (mm[3] == -INFINITY) ? 0.f : mm[3]);    \
    u32x2 u;                                                                \
    u.x = *(unsigned int*)&h01;                                             \
    u.y = *(unsigned int*)&h23;                                             \
    *(u32x2*)&Asm[w * 16 + q * 4 + i][ch0] = u; }
    STORE(m0, 0) STORE(m1, 1) STORE(m2, 2) STORE(m3, 3)
#undef STORE
  }
  // NO block barrier: wave w's GEMM reads only Asm rows 16w..16w+15 (written by
  // this wave); intra-wave ds_write->ds_read ordering via lgkmcnt.

  // ---- MFMA GEMM ----
  f32x4 acc[4];
#pragma unroll
  for (int t = 0; t < 4; ++t) acc[t] = (f32x4){0.f, 0.f, 0.f, 0.f};
#pragma unroll
  for (int kc = 0; kc < 4; ++kc) {
    const int kof = kc * 32 + lg * 8;
    f16x8 a = (kc == 0) ? aself0
            : (kc == 1) ? aself1
                        : *(const f16x8*)&Asm[w * 16 + lr][kof - 64];
#pragma unroll
    for (int t = 0; t < 4; ++t) {
      f16x8 bf = *(const f16x8*)&Wt[t * 16 + lr][kof];
      acc[t] = __builtin_amdgcn_mfma_f32_16x16x32_f16(a, bf, acc[t], 0, 0, 0);
    }
  }

  // ---- epilogue: +bias, relu, BN, relu ----
  float o[4][4];
#pragma unroll
  for (int t = 0; t < 4; ++t) {
    int cc = t * 16 + lr;
    float bias = b[cc];
    float sc = gam[cc] * rsqrtf(var[cc] + 1e-5f);
    float sh = bet[cc] - mean[cc] * sc;
#pragma unroll
    for (int r = 0; r < 4; ++r) {
      float v = fmaxf(acc[t][r] + bias, 0.f);
      o[t][r] = fmaxf(fmaf(v, sc, sh), 0.f);
    }
  }

  const int rbase = nb + w * 16 + lg * 4;
  if (!last) {
#pragma unroll
    for (int r = 0; r < 4; ++r) {
      int n = rbase + r;
      if (n < Nn) {
#pragma unroll
        for (int t = 0; t < 4; ++t)
          out16[n * HC + t * 16 + lr] = __float2half(o[t][r]);
      }
    }
    return;
  }

  // ---- last layer: fused predictor (waves reconverge here) ----
  __syncthreads();  // all waves done with GEMM1 (Wt reads) before overwrite
#pragma unroll
  for (int t = 0; t < 4; ++t)
#pragma unroll
    for (int r = 0; r < 4; ++r)
      Asm[w * 16 + lg * 4 + r][t * 16 + lr] = __float2half(o[t][r]);
  for (int i = tid; i < 64 * 64; i += 256) {
    int k = i >> 6, col = i & 63;
    Wt[col][k] = __float2half(Wp1[i]);
  }
  __syncthreads();

  f32x4 acc2[4];
#pragma unroll
  for (int t = 0; t < 4; ++t) acc2[t] = (f32x4){0.f, 0.f, 0.f, 0.f};
#pragma unroll
  for (int kc = 0; kc < 2; ++kc) {
    const int kof = kc * 32 + lg * 8;
    f16x8 a = *(const f16x8*)&Asm[w * 16 + lr][kof];
#pragma unroll
    for (int t = 0; t < 4; ++t) {
      f16x8 bf = *(const f16x8*)&Wt[t * 16 + lr][kof];
      acc2[t] = __builtin_amdgcn_mfma_f32_16x16x32_f16(a, bf, acc2[t], 0, 0, 0);
    }
  }

  float s[4] = {0.f, 0.f, 0.f, 0.f};
#pragma unroll
  for (int t = 0; t < 4; ++t) {
    int cc = t * 16 + lr;
    float b1 = bp1[cc], w2 = Wp2[cc];
#pragma unroll
    for (int r = 0; r < 4; ++r) {
      float pv = fmaxf(acc2[t][r] + b1, 0.f);
      s[r] = fmaf(pv, w2, s[r]);
    }
  }
#pragma unroll
  for (int msk = 1; msk < 16; msk <<= 1) {
#pragma unroll
    for (int r = 0; r < 4; ++r) s[r] += __shfl_xor(s[r], msk, 64);
  }
  if (lr == 0) {
    float b2 = bp2[0];
#pragma unroll
    for (int r = 0; r < 4; ++r) {
      int n = rbase + r;
      if (n < Nn) pred[n] = s[r] + b2;
    }
  }
}

extern "C" void kernel_launch(void* const* d_in, const int* in_sizes, int n_in,
                              void* d_out, int out_size, void* d_ws, size_t ws_size,
                              hipStream_t stream) {
  const float* x = (const float*)d_in[0];
  const int* eidx = (const int*)d_in[1];
  const float* eattr = (const float*)d_in[2];
  const float* Wenc = (const float*)d_in[3];
  const float* benc = (const float*)d_in[4];
  const float* Wedge = (const float*)d_in[5];
  const float* bedge = (const float*)d_in[6];
  const float* Wupd = (const float*)d_in[7];
  const float* bupd = (const float*)d_in[8];
  const float* bng = (const float*)d_in[9];
  const float* bnb = (const float*)d_in[10];
  const float* bnm = (const float*)d_in[11];
  const float* bnv = (const float*)d_in[12];
  const float* Wp1 = (const float*)d_in[13];
  const float* bp1 = (const float*)d_in[14];
  const float* Wp2 = (const float*)d_in[15];
  const float* bp2 = (const float*)d_in[16];

  const int Nn = in_sizes[0] / FIN;
  const int E = in_sizes[1] / 2;
  const int* src = eidx;
  const int* dst = eidx + E;
  const int NH = Nn * HC;

  size_t off = 0;
  char* base = (char*)d_ws;
  auto carve = [&](size_t bytes) -> void* {
    void* p = base + off;
    off += (bytes + 255) & ~(size_t)255;
    return p;
  };
  int* counts = (int*)carve((size_t)Nn * 4);
  unsigned int* bucket = (unsigned int*)carve((size_t)Nn * CAP * 4);
  __half* hA16 = (__half*)carve((size_t)NH * 2);
  __half* hB16 = (__half*)carve((size_t)NH * 2);
  if (off > ws_size) return;

  int nhB = (Nn * (HC / 4) + 255) / 256;
  int edgeB8 = 8 * ((E + ECHUNK - 1) / ECHUNK);
  int updB = (Nn + 63) / 64;

  hipMemsetAsync(counts, 0, (size_t)Nn * 4, stream);
  k_enc_scatter<<<edgeB8 + nhB, 256, 0, stream>>>(x, Wenc, benc, hA16, Nn,
                                                  src, dst, eattr, counts, bucket, E, edgeB8);

  __half* hc16 = hA16;
  __half* hn16 = hB16;
  for (int i = 0; i < LAYERS; ++i) {
    int last = (i == LAYERS - 1) ? 1 : 0;
    k_layer<<<updB, 256, 0, stream>>>(hc16, counts, bucket,
                                      Wedge + i * HC, bedge + i * HC,
                                      Wupd + i * 2 * HC * HC, bupd + i * HC,
                                      bng + i * HC, bnb + i * HC, bnm + i * HC, bnv + i * HC,
                                      hn16, Nn,
                                      last, Wp1, bp1, Wp2, bp2, (float*)d_out);
    __half* t16 = hc16; hc16 = hn16; hn16 = t16;
  }
}

// Round 11
// 350.018 us; speedup vs baseline: 1.2340x; 1.2340x over previous
//
#include <hip/hip_runtime.h>
#include <hip/hip_fp16.h>

#define FIN 6
#define HC 64
#define LAYERS 3
#define CAP 48       // bucket slots per node; Poisson(12) tail @48 ~ 8e-16
#define ECHUNK 2048  // edges per scatter block

typedef _Float16 f16x8 __attribute__((ext_vector_type(8)));
typedef float f32x4 __attribute__((ext_vector_type(4)));
typedef unsigned int u32x2 __attribute__((ext_vector_type(2)));

__global__ void PathfindingGNN_17274358464713_kernel() {}

// ---- fused: partitioned edge scatter (8 node-range passes, XCD-local L2 slices)
//      + encoder (h16, 4ch/thread) ---- [round-7 proven: ~71us]
__global__ __launch_bounds__(256) void k_enc_scatter(const float* __restrict__ x,
                                                     const float* __restrict__ Wenc,
                                                     const float* __restrict__ benc,
                                                     __half* __restrict__ h16,
                                                     int Nn,
                                                     const int* __restrict__ src,
                                                     const int* __restrict__ dst,
                                                     const float* __restrict__ ea,
                                                     int* __restrict__ counts,
                                                     unsigned int* __restrict__ bucket,
                                                     int E, int edgeB8) {
  if ((int)blockIdx.x < edgeB8) {
    const int part = blockIdx.x & 7;
    const int chunk = blockIdx.x >> 3;
    const int e0 = chunk * ECHUNK;
    const int e1 = min(e0 + ECHUNK, E);
    int dv[8], sv[8];
    float eav[8];
#pragma unroll
    for (int j = 0; j < 8; ++j) {
      int e = e0 + (int)threadIdx.x + j * 256;
      if (e < e1) {
        dv[j] = __builtin_nontemporal_load(&dst[e]);
        sv[j] = __builtin_nontemporal_load(&src[e]);
        eav[j] = __builtin_nontemporal_load(&ea[e]);
      } else {
        dv[j] = -1;
      }
    }
#pragma unroll
    for (int j = 0; j < 8; ++j) {
      int d = dv[j];
      if (d < 0) continue;
      int p8 = (int)(((unsigned int)d * 41u) >> 19);
      if (p8 != part) continue;
      int p = atomicAdd(&counts[d], 1);
      if (p < CAP) {
        unsigned int q = (unsigned int)(eav[j] * 32767.0f + 0.5f);  // ea in [0,1)
        bucket[d * CAP + p] = (unsigned int)sv[j] | (q << 17);
      }
    }
    return;
  }
  int idx = (blockIdx.x - edgeB8) * 256 + threadIdx.x;
  if (idx >= Nn * (HC / 4)) return;
  int n = idx >> 4, cp = (idx & 15) * 4;
  float4 bv = *(const float4*)&benc[cp];
  float s0 = bv.x, s1 = bv.y, s2 = bv.z, s3 = bv.w;
#pragma unroll
  for (int f = 0; f < FIN; ++f) {
    float xv = x[n * FIN + f];
    float4 wv = *(const float4*)&Wenc[f * HC + cp];
    s0 = fmaf(xv, wv.x, s0);
    s1 = fmaf(xv, wv.y, s1);
    s2 = fmaf(xv, wv.z, s2);
    s3 = fmaf(xv, wv.w, s3);
  }
  __half2 h01 = __floats2half2_rn(s0, s1);
  __half2 h23 = __floats2half2_rn(s2, s3);
  u32x2 u;
  u.x = *(unsigned int*)&h01;
  u.y = *(unsigned int*)&h23;
  *(u32x2*)&h16[n * HC + cp] = u;  // cached: k_layer re-reads h16 ~12x
}

// ---------------- fused layer: round-7 gather (2-phase, register-safe) +
//                  BARRIER-FREE wave pipeline + MFMA GEMM + BN (+predictor) ----
// 64 nodes/block, 256 threads (4 waves). Structure: stage Wt -> ONE barrier ->
// each wave runs gather -> GEMM -> epilogue -> store independently (wave w's GEMM
// reads only Asm rows 16w..16w+15, written only by wave w; intra-wave LDS ordering
// via lgkmcnt). Gather per quarter-wave: 2 phases x 2 nodes, 8 uint4 prefetch per
// phase (32 VGPR -- fits (256,6) budget; r8/r10 lesson: 16-uint4 single-phase
// SPILLS to scratch at VGPR 40 -> +28MB fetch +79MB write + 140us first-dispatch).
__global__ __launch_bounds__(256, 6) void k_layer(const __half* __restrict__ h16,
                                                  const int* __restrict__ counts,
                                                  const unsigned int* __restrict__ bucket,
                                                  const float* __restrict__ We, const float* __restrict__ be,
                                                  const float* __restrict__ W, const float* __restrict__ b,
                                                  const float* __restrict__ gam, const float* __restrict__ bet,
                                                  const float* __restrict__ mean, const float* __restrict__ var,
                                                  __half* __restrict__ out16, int Nn,
                                                  int last, const float* __restrict__ Wp1,
                                                  const float* __restrict__ bp1, const float* __restrict__ Wp2,
                                                  const float* __restrict__ bp2, float* __restrict__ pred) {
  __shared__ alignas(16) __half Wt[64][136];  // Wt[col][k] = W[k][col], k<128
  __shared__ alignas(16) __half Asm[64][72];  // agg fp16 (wave-private row bands)

  const int tid = threadIdx.x;
  const int nb = blockIdx.x * 64;
  const int w = tid >> 6;
  const int lr = tid & 15;
  const int lg = (tid >> 4) & 3;
  const float inv15 = 1.0f / 32767.0f;

  // issue gather-critical + GEMM-self loads FIRST (in flight across Wt staging)
  int ldn = min(nb + w * 16 + lr, Nn - 1);
  int ldc = min(counts[ldn], CAP);
  const int arow = ldn;
  f16x8 aself0 = *(const f16x8*)&h16[arow * HC + lg * 8];
  f16x8 aself1 = *(const f16x8*)&h16[arow * HC + 32 + lg * 8];

  // stage Wt, then the ONLY pre-GEMM barrier
  for (int i = tid; i < 128 * 64; i += 256) {
    int k = i >> 6, col = i & 63;
    Wt[col][k] = __float2half(W[i]);
  }
  __syncthreads();

  // ---- gather (wave-independent from here) ----
  {
    const int q = (tid >> 4) & 3;
    const int ch0 = (tid & 15) * 4;
    const float4 wev = *(const float4*)&We[ch0];
    const float4 bev = *(const float4*)&be[ch0];

#define PROC(vv, mm) {                                                      \
    unsigned int v_ = (vv);                                                 \
    u32x2 hu = *(const u32x2*)&h16[(v_ & 0x1FFFFu) * HC + ch0];             \
    unsigned int hx_ = hu.x, hy_ = hu.y;                                    \
    float qf = (float)(v_ >> 17) * inv15;                                   \
    float2 f01 = __half22float2(*(const __half2*)&hx_);                     \
    float2 f23 = __half22float2(*(const __half2*)&hy_);                     \
    mm[0] = fmaxf(mm[0], f01.x * fmaf(qf, wev.x, bev.x));                   \
    mm[1] = fmaxf(mm[1], f01.y * fmaf(qf, wev.y, bev.y));                   \
    mm[2] = fmaxf(mm[2], f23.x * fmaf(qf, wev.z, bev.z));                   \
    mm[3] = fmaxf(mm[3], f23.y * fmaf(qf, wev.w, bev.w)); }

    for (int it = 0; it < 2; ++it) {
      const int iA = q * 4 + it, iB = iA + 2;
      const int nlA = w * 16 + iA, nlB = w * 16 + iB;
      const int cA = __shfl(ldc, iA, 64);
      const int cB = __shfl(ldc, iB, 64);
      const int r0A = min(nb + nlA, Nn - 1) * CAP;
      const int r0B = min(nb + nlB, Nn - 1) * CAP;
      // unconditional upfront prefetch: 8 uint4 = 32 records in flight (32 VGPR)
      uint4 pa[4], pb[4];
#pragma unroll
      for (int j = 0; j < 4; ++j) pa[j] = *(const uint4*)&bucket[r0A + 4 * j];
#pragma unroll
      for (int j = 0; j < 4; ++j) pb[j] = *(const uint4*)&bucket[r0B + 4 * j];
      float ma[4], mb[4];
#pragma unroll
      for (int i = 0; i < 4; ++i) { ma[i] = -INFINITY; mb[i] = -INFINITY; }
#pragma unroll
      for (int j = 0; j < 4; ++j) {
        const int base = 4 * j;
        if (cA > base)     PROC(pa[j].x, ma)
        if (cB > base)     PROC(pb[j].x, mb)
        if (cA > base + 1) PROC(pa[j].y, ma)
        if (cB > base + 1) PROC(pb[j].y, mb)
        if (cA > base + 2) PROC(pa[j].z, ma)
        if (cB > base + 2) PROC(pb[j].z, mb)
        if (cA > base + 3) PROC(pa[j].w, ma)
        if (cB > base + 3) PROC(pb[j].w, mb)
      }
      // tails (cnt > 16, rare)
      for (int r = r0A + 16, r1 = r0A + cA; r < r1; ++r) PROC(bucket[r], ma)
      for (int r = r0B + 16, r1 = r0B + cB; r < r1; ++r) PROC(bucket[r], mb)
#define STOREM(mm, nl) {                                                    \
      __half2 h01 = __floats2half2_rn((mm[0] == -INFINITY) ? 0.f : mm[0],   \
                                      (mm[1] == -INFINITY) ? 0.f : mm[1]);  \
      __half2 h23 = __floats2half2_rn((mm[2] == -INFINITY) ? 0.f : mm[2],   \
                                      (mm[3] == -INFINITY) ? 0.f : mm[3]);  \
      u32x2 u;                                                              \
      u.x = *(unsigned int*)&h01;                                           \
      u.y = *(unsigned int*)&h23;                                           \
      *(u32x2*)&Asm[nl][ch0] = u; }
      STOREM(ma, nlA)
      STOREM(mb, nlB)
#undef STOREM
    }
#undef PROC
  }
  // NO block barrier: wave w's GEMM reads only its own Asm rows.

  // ---- MFMA GEMM: wave w owns rows 16w..16w+15, 4 col-tiles, K=128 in 4 chunks ----
  // A frag: row = lane&15, k = 8*(lane>>4)+j (kc<2: self-h preloaded; kc>=2: agg LDS)
  // B frag: col = lane&15, same k mapping, from Wt (k-contiguous)
  // C/D:    col = lane&15, row = 4*(lane>>4)+reg   [m89-verified]
  f32x4 acc[4];
#pragma unroll
  for (int t = 0; t < 4; ++t) acc[t] = (f32x4){0.f, 0.f, 0.f, 0.f};
#pragma unroll
  for (int kc = 0; kc < 4; ++kc) {
    const int kof = kc * 32 + lg * 8;
    f16x8 a = (kc == 0) ? aself0
            : (kc == 1) ? aself1
                        : *(const f16x8*)&Asm[w * 16 + lr][kof - 64];
#pragma unroll
    for (int t = 0; t < 4; ++t) {
      f16x8 bf = *(const f16x8*)&Wt[t * 16 + lr][kof];
      acc[t] = __builtin_amdgcn_mfma_f32_16x16x32_f16(a, bf, acc[t], 0, 0, 0);
    }
  }

  // ---- epilogue: +bias, relu, BN, relu ----
  float o[4][4];
#pragma unroll
  for (int t = 0; t < 4; ++t) {
    int cc = t * 16 + lr;
    float bias = b[cc];
    float sc = gam[cc] * rsqrtf(var[cc] + 1e-5f);
    float sh = bet[cc] - mean[cc] * sc;
#pragma unroll
    for (int r = 0; r < 4; ++r) {
      float v = fmaxf(acc[t][r] + bias, 0.f);
      o[t][r] = fmaxf(fmaf(v, sc, sh), 0.f);
    }
  }

  const int rbase = nb + w * 16 + lg * 4;
  if (!last) {
#pragma unroll
    for (int r = 0; r < 4; ++r) {
      int n = rbase + r;
      if (n < Nn) {
#pragma unroll
        for (int t = 0; t < 4; ++t)
          out16[n * HC + t * 16 + lr] = __float2half(o[t][r]);
      }
    }
    return;
  }

  // ---- last layer: fused predictor (waves reconverge here) ----
  __syncthreads();  // all waves done with GEMM1 (Wt reads) before overwrite
#pragma unroll
  for (int t = 0; t < 4; ++t)
#pragma unroll
    for (int r = 0; r < 4; ++r)
      Asm[w * 16 + lg * 4 + r][t * 16 + lr] = __float2half(o[t][r]);
  for (int i = tid; i < 64 * 64; i += 256) {
    int k = i >> 6, col = i & 63;
    Wt[col][k] = __float2half(Wp1[i]);
  }
  __syncthreads();

  f32x4 acc2[4];
#pragma unroll
  for (int t = 0; t < 4; ++t) acc2[t] = (f32x4){0.f, 0.f, 0.f, 0.f};
#pragma unroll
  for (int kc = 0; kc < 2; ++kc) {
    const int kof = kc * 32 + lg * 8;
    f16x8 a = *(const f16x8*)&Asm[w * 16 + lr][kof];
#pragma unroll
    for (int t = 0; t < 4; ++t) {
      f16x8 bf = *(const f16x8*)&Wt[t * 16 + lr][kof];
      acc2[t] = __builtin_amdgcn_mfma_f32_16x16x32_f16(a, bf, acc2[t], 0, 0, 0);
    }
  }

  float s[4] = {0.f, 0.f, 0.f, 0.f};
#pragma unroll
  for (int t = 0; t < 4; ++t) {
    int cc = t * 16 + lr;
    float b1 = bp1[cc], w2 = Wp2[cc];
#pragma unroll
    for (int r = 0; r < 4; ++r) {
      float pv = fmaxf(acc2[t][r] + b1, 0.f);
      s[r] = fmaf(pv, w2, s[r]);
    }
  }
#pragma unroll
  for (int msk = 1; msk < 16; msk <<= 1) {
#pragma unroll
    for (int r = 0; r < 4; ++r) s[r] += __shfl_xor(s[r], msk, 64);
  }
  if (lr == 0) {
    float b2 = bp2[0];
#pragma unroll
    for (int r = 0; r < 4; ++r) {
      int n = rbase + r;
      if (n < Nn) pred[n] = s[r] + b2;
    }
  }
}

extern "C" void kernel_launch(void* const* d_in, const int* in_sizes, int n_in,
                              void* d_out, int out_size, void* d_ws, size_t ws_size,
                              hipStream_t stream) {
  const float* x = (const float*)d_in[0];
  const int* eidx = (const int*)d_in[1];
  const float* eattr = (const float*)d_in[2];
  const float* Wenc = (const float*)d_in[3];
  const float* benc = (const float*)d_in[4];
  const float* Wedge = (const float*)d_in[5];
  const float* bedge = (const float*)d_in[6];
  const float* Wupd = (const float*)d_in[7];
  const float* bupd = (const float*)d_in[8];
  const float* bng = (const float*)d_in[9];
  const float* bnb = (const float*)d_in[10];
  const float* bnm = (const float*)d_in[11];
  const float* bnv = (const float*)d_in[12];
  const float* Wp1 = (const float*)d_in[13];
  const float* bp1 = (const float*)d_in[14];
  const float* Wp2 = (const float*)d_in[15];
  const float* bp2 = (const float*)d_in[16];

  const int Nn = in_sizes[0] / FIN;
  const int E = in_sizes[1] / 2;
  const int* src = eidx;
  const int* dst = eidx + E;
  const int NH = Nn * HC;

  size_t off = 0;
  char* base = (char*)d_ws;
  auto carve = [&](size_t bytes) -> void* {
    void* p = base + off;
    off += (bytes + 255) & ~(size_t)255;
    return p;
  };
  int* counts = (int*)carve((size_t)Nn * 4);
  unsigned int* bucket = (unsigned int*)carve((size_t)Nn * CAP * 4);
  __half* hA16 = (__half*)carve((size_t)NH * 2);
  __half* hB16 = (__half*)carve((size_t)NH * 2);
  if (off > ws_size) return;

  int nhB = (Nn * (HC / 4) + 255) / 256;
  int edgeB8 = 8 * ((E + ECHUNK - 1) / ECHUNK);
  int updB = (Nn + 63) / 64;

  hipMemsetAsync(counts, 0, (size_t)Nn * 4, stream);
  k_enc_scatter<<<edgeB8 + nhB, 256, 0, stream>>>(x, Wenc, benc, hA16, Nn,
                                                  src, dst, eattr, counts, bucket, E, edgeB8);

  __half* hc16 = hA16;
  __half* hn16 = hB16;
  for (int i = 0; i < LAYERS; ++i) {
    int last = (i == LAYERS - 1) ? 1 : 0;
    k_layer<<<updB, 256, 0, stream>>>(hc16, counts, bucket,
                                      Wedge + i * HC, bedge + i * HC,
                                      Wupd + i * 2 * HC * HC, bupd + i * HC,
                                      bng + i * HC, bnb + i * HC, bnm + i * HC, bnv + i * HC,
                                      hn16, Nn,
                                      last, Wp1, bp1, Wp2, bp2, (float*)d_out);
    __half* t16 = hc16; hc16 = hn16; hn16 = t16;
  }
}